// Round 1
// baseline (559.715 us; speedup 1.0000x reference)
//
#include <hip/hip_runtime.h>
#include <hip/hip_bf16.h>

// MoE top-2/8, T=4096, H=2048, FFN=1024.
// Fused-conversion pipeline (no bf16 weight copies in HBM):
//   router  (router logits + x fp32->bf16 -> Xb)
//   compact (1 block, ballot prefix)
//   upproj  (A=Xb bf16 via global_load_lds; B=W1/W3 fp32 -> reg convert -> LDS)
//   downproj(A=G bf16 via global_load_lds;  B=W2 fp32 -> reg convert -> LDS)
//   combine

#define T_TOK 4096
#define H_DIM 2048
#define FFN_D 1024
#define NE    8

typedef __attribute__((ext_vector_type(8))) short          bf16x8;
typedef __attribute__((ext_vector_type(4))) float          f32x4;
typedef __attribute__((ext_vector_type(4))) unsigned short us4;
typedef __attribute__((ext_vector_type(8))) unsigned short us8;

#define RB_ROUTER 1024u

__device__ __forceinline__ unsigned short f2bf(float f) {
  unsigned u = __builtin_bit_cast(unsigned, f);
  u += 0x7fffu + ((u >> 16) & 1u);
  return (unsigned short)(u >> 16);
}
__device__ __forceinline__ float bf2f(unsigned short u) {
  return __builtin_bit_cast(float, ((unsigned)u) << 16);
}
__device__ __forceinline__ us8 f8bf(float4 a, float4 b) {
  us8 o;
  o[0] = f2bf(a.x); o[1] = f2bf(a.y); o[2] = f2bf(a.z); o[3] = f2bf(a.w);
  o[4] = f2bf(b.x); o[5] = f2bf(b.y); o[6] = f2bf(b.z); o[7] = f2bf(b.w);
  return o;
}
__device__ __forceinline__ void async16(const void* g, void* l) {
  __builtin_amdgcn_global_load_lds((const __attribute__((address_space(1))) void*)g,
                                   (__attribute__((address_space(3))) void*)l, 16, 0, 0);
}

// ---------------- K1: router (one wave per token) + x convert -> Xb ----
__global__ void router_kernel(const float* __restrict__ x,
                              const float* __restrict__ Wg,
                              const float* __restrict__ bias,
                              unsigned* __restrict__ epair,
                              float* __restrict__ wpair,
                              unsigned short* __restrict__ Xb) {
  const int wv   = threadIdx.x >> 6;
  const int lane = threadIdx.x & 63;
  const int t    = blockIdx.x * 4 + wv;

  const float4* xr = (const float4*)(x + (size_t)t * H_DIM);
  us4*          xb = (us4*)(Xb + (size_t)t * H_DIM);

  float acc[NE];
#pragma unroll
  for (int e = 0; e < NE; e++) acc[e] = 0.f;

#pragma unroll
  for (int j = 0; j < 8; j++) {
    int i4 = j * 64 + lane;
    float4 v = xr[i4];
    us4 d; d.x = f2bf(v.x); d.y = f2bf(v.y); d.z = f2bf(v.z); d.w = f2bf(v.w);
    xb[i4] = d;
#pragma unroll
    for (int e = 0; e < NE; e++) {
      float4 w = ((const float4*)(Wg + e * H_DIM))[i4];
      acc[e] += v.x * w.x + v.y * w.y + v.z * w.z + v.w * w.w;
    }
  }
#pragma unroll
  for (int e = 0; e < NE; e++) {
#pragma unroll
    for (int m = 32; m >= 1; m >>= 1) acc[e] += __shfl_xor(acc[e], m, 64);
  }

  if (lane == 0) {
    float sig[NE], sc[NE];
#pragma unroll
    for (int e = 0; e < NE; e++) {
      sig[e] = 1.f / (1.f + expf(-acc[e]));
      sc[e]  = sig[e] + bias[e];
    }
    int i1 = 0; float v1 = sc[0];
#pragma unroll
    for (int e = 1; e < NE; e++) if (sc[e] > v1) { v1 = sc[e]; i1 = e; }
    int i2 = -1; float v2 = -1e30f;
#pragma unroll
    for (int e = 0; e < NE; e++) if (e != i1 && sc[e] > v2) { v2 = sc[e]; i2 = e; }
    float w1 = sig[i1], w2 = sig[i2];
    float s = w1 + w2;
    epair[t] = (unsigned)i1 | ((unsigned)i2 << 8);
    wpair[2 * t]     = w1 / s;
    wpair[2 * t + 1] = w2 / s;
  }
}

// ---------------- K2: compaction, ONE block, 8 waves (wave e scans all tokens) ----
__global__ void compact_kernel(const unsigned* __restrict__ epair,
                               const float* __restrict__ wpair,
                               int* __restrict__ cnt,
                               int* __restrict__ base,
                               int* __restrict__ rows,
                               float* __restrict__ wts,
                               int* __restrict__ t2s) {
  const int e    = threadIdx.x >> 6;
  const int lane = threadIdx.x & 63;
  const unsigned long long ltmask = ((unsigned long long)1 << lane) - 1;
  __shared__ int cnts[NE];

  int count = 0;
  for (int c = 0; c < T_TOK; c += 64) {
    int t = c + lane;
    unsigned ep = epair[t];
    bool m1 = ((ep & 255u) == (unsigned)e);
    bool m2 = (((ep >> 8) & 255u) == (unsigned)e);
    unsigned long long b1 = __ballot(m1);
    if (m1) {
      int p = count + __popcll(b1 & ltmask);
      rows[e * T_TOK + p] = t;
      wts [e * T_TOK + p] = wpair[2 * t];
      t2s[2 * t] = (e << 12) | p;
    }
    count += __popcll(b1);
    unsigned long long b2 = __ballot(m2);
    if (m2) {
      int p = count + __popcll(b2 & ltmask);
      rows[e * T_TOK + p] = t;
      wts [e * T_TOK + p] = wpair[2 * t + 1];
      t2s[2 * t + 1] = (e << 12) | p;
    }
    count += __popcll(b2);
  }
  if (lane == 0) { cnts[e] = count; cnt[e] = count; }
  __syncthreads();
  if (threadIdx.x == 0) {
    int s = 0;
    for (int i = 0; i < NE; i++) { base[i] = s; s += cnts[i]; }
    base[NE] = s;
  }
}

// ---------------- K3: up-proj BM=128 x BN=64 (x2 mats), BK=32.
// B operand staged from fp32 W1/W3 with in-register bf16 convert. ----
__launch_bounds__(256)
__global__ void upproj_fast(const unsigned short* __restrict__ Xb,
                            const float* __restrict__ W1,
                            const float* __restrict__ W3,
                            const int* __restrict__ cnt,
                            const int* __restrict__ base,
                            const int* __restrict__ rows,
                            const float* __restrict__ wts,
                            unsigned short* __restrict__ G) {
  const int e  = blockIdx.z;
  const int m0 = blockIdx.y * 128;
  const int n0 = blockIdx.x * 64;
  const int ce = cnt[e];
  if (m0 >= ce) return;

  __shared__ __align__(16) unsigned short As [128 * 32];
  __shared__ __align__(16) unsigned short B1s[64 * 32];
  __shared__ __align__(16) unsigned short B3s[64 * 32];
  __shared__ int   t_ids[128];
  __shared__ float w_lds[128];

  const int tid = threadIdx.x;
  if (tid < 128) {
    int i = m0 + tid;
    if (i < ce) { t_ids[tid] = rows[e * T_TOK + i]; w_lds[tid] = wts[e * T_TOK + i]; }
    else        { t_ids[tid] = 0;                   w_lds[tid] = 0.f; }
  }
  __syncthreads();

  const int lane = tid & 63;
  const int wv   = tid >> 6;

  const unsigned short* gA[2];
#pragma unroll
  for (int c = 0; c < 2; c++) {
    int r = wv * 32 + c * 16 + (lane >> 2);
    gA[c] = Xb + (size_t)t_ids[r] * H_DIM + (lane & 3) * 8;
  }
  unsigned short* lA0 = &As[(wv * 32 + 0)  * 32];
  unsigned short* lA1 = &As[(wv * 32 + 16) * 32];

  // B: fp32 source, reg-convert, LDS layout identical to the old bf16 path
  const int brow = n0 + wv * 16 + (lane >> 2);
  const float* gB1 = W1 + (size_t)e * FFN_D * H_DIM + (size_t)brow * H_DIM + (lane & 3) * 8;
  const float* gB3 = W3 + (size_t)e * FFN_D * H_DIM + (size_t)brow * H_DIM + (lane & 3) * 8;
  const int bidx = (wv * 16 + (lane >> 2)) * 32 + (lane & 3) * 8;

  const int wm = (wv & 1) * 64;
  const int wn = (wv >> 1) * 32;
  const int qk = (lane >> 4) * 8;
  const int lr = lane & 15;

  f32x4 acc1[4][2], acc3[4][2];
#pragma unroll
  for (int mi = 0; mi < 4; mi++)
#pragma unroll
    for (int ni = 0; ni < 2; ni++) { acc1[mi][ni] = (f32x4)0.f; acc3[mi][ni] = (f32x4)0.f; }

  // prologue: load first B K-slab into regs
  float4 p0 = *(const float4*)(gB1 + 0);
  float4 p1 = *(const float4*)(gB1 + 4);
  float4 p2 = *(const float4*)(gB3 + 0);
  float4 p3 = *(const float4*)(gB3 + 4);

  for (int kt = 0; kt < H_DIM; kt += 32) {
    async16(gA[0] + kt, lA0);
    async16(gA[1] + kt, lA1);

    float4 c0 = p0, c1 = p1, c2 = p2, c3 = p3;
    int ktn = (kt + 32 < H_DIM) ? kt + 32 : kt;   // clamped prefetch (last iter harmless)
    p0 = *(const float4*)(gB1 + ktn);
    p1 = *(const float4*)(gB1 + ktn + 4);
    p2 = *(const float4*)(gB3 + ktn);
    p3 = *(const float4*)(gB3 + ktn + 4);

    *(us8*)&B1s[bidx] = f8bf(c0, c1);
    *(us8*)&B3s[bidx] = f8bf(c2, c3);
    __syncthreads();

    bf16x8 a[4], b1[2], b3[2];
#pragma unroll
    for (int mi = 0; mi < 4; mi++)
      a[mi] = *(const bf16x8*)&As[(wm + mi * 16 + lr) * 32 + qk];
#pragma unroll
    for (int ni = 0; ni < 2; ni++) {
      b1[ni] = *(const bf16x8*)&B1s[(wn + ni * 16 + lr) * 32 + qk];
      b3[ni] = *(const bf16x8*)&B3s[(wn + ni * 16 + lr) * 32 + qk];
    }
#pragma unroll
    for (int mi = 0; mi < 4; mi++)
#pragma unroll
      for (int ni = 0; ni < 2; ni++) {
        acc1[mi][ni] = __builtin_amdgcn_mfma_f32_16x16x32_bf16(a[mi], b1[ni], acc1[mi][ni], 0, 0, 0);
        acc3[mi][ni] = __builtin_amdgcn_mfma_f32_16x16x32_bf16(a[mi], b3[ni], acc3[mi][ni], 0, 0, 0);
      }
    __syncthreads();
  }

  const int be = base[e];
#pragma unroll
  for (int mi = 0; mi < 4; mi++)
#pragma unroll
    for (int ni = 0; ni < 2; ni++)
#pragma unroll
      for (int r = 0; r < 4; r++) {
        int row = wm + mi * 16 + (lane >> 4) * 4 + r;
        int col = wn + ni * 16 + lr;
        int i = m0 + row;
        if (i < ce) {
          float h1 = acc1[mi][ni][r];
          float h3 = acc3[mi][ni][r];
          float g  = h1 / (1.f + expf(-h1)) * h3 * w_lds[row];
          G[(size_t)(be + i) * FFN_D + n0 + col] = f2bf(g);
        }
      }
}

// ---------------- K4: down-proj BM=128 x BN=128, BK=32 -> bf16 Gd.
// B operand staged from fp32 W2 with in-register bf16 convert. ----
__launch_bounds__(256)
__global__ void downproj_fast(const unsigned short* __restrict__ G,
                              const float* __restrict__ W2,
                              const int* __restrict__ cnt,
                              const int* __restrict__ base,
                              unsigned short* __restrict__ Gd) {
  const int e  = blockIdx.z;
  const int m0 = blockIdx.y * 128;
  const int n0 = blockIdx.x * 128;
  const int ce = cnt[e];
  if (m0 >= ce) return;
  const int be = base[e];

  __shared__ __align__(16) unsigned short As[128 * 32];
  __shared__ __align__(16) unsigned short Bs[128 * 32];

  const int tid  = threadIdx.x;
  const int lane = tid & 63;
  const int wv   = tid >> 6;

  const unsigned short* gA[2];
#pragma unroll
  for (int c = 0; c < 2; c++) {
    int r = m0 + wv * 32 + c * 16 + (lane >> 2);
    if (r >= ce) r = ce - 1;
    gA[c] = G + (size_t)(be + r) * FFN_D + (lane & 3) * 8;
  }
  unsigned short* lA[2] = { &As[(wv * 32 + 0) * 32], &As[(wv * 32 + 16) * 32] };

  // B rows from fp32 W2
  const int rb0 = wv * 32 + (lane >> 2);
  const int rb1 = rb0 + 16;
  const float* gB0 = W2 + (size_t)e * H_DIM * FFN_D + (size_t)(n0 + rb0) * FFN_D + (lane & 3) * 8;
  const float* gB1 = W2 + (size_t)e * H_DIM * FFN_D + (size_t)(n0 + rb1) * FFN_D + (lane & 3) * 8;
  const int bi0 = rb0 * 32 + (lane & 3) * 8;
  const int bi1 = rb1 * 32 + (lane & 3) * 8;

  const int wm = (wv & 1) * 64;
  const int wn = (wv >> 1) * 64;
  const int qk = (lane >> 4) * 8;
  const int lr = lane & 15;

  f32x4 acc[4][4];
#pragma unroll
  for (int mi = 0; mi < 4; mi++)
#pragma unroll
    for (int ni = 0; ni < 4; ni++) acc[mi][ni] = (f32x4)0.f;

  // prologue B regs
  float4 p0 = *(const float4*)(gB0 + 0);
  float4 p1 = *(const float4*)(gB0 + 4);
  float4 p2 = *(const float4*)(gB1 + 0);
  float4 p3 = *(const float4*)(gB1 + 4);

  for (int kt = 0; kt < FFN_D; kt += 32) {
    async16(gA[0] + kt, lA[0]);
    async16(gA[1] + kt, lA[1]);

    float4 c0 = p0, c1 = p1, c2 = p2, c3 = p3;
    int ktn = (kt + 32 < FFN_D) ? kt + 32 : kt;
    p0 = *(const float4*)(gB0 + ktn);
    p1 = *(const float4*)(gB0 + ktn + 4);
    p2 = *(const float4*)(gB1 + ktn);
    p3 = *(const float4*)(gB1 + ktn + 4);

    *(us8*)&Bs[bi0] = f8bf(c0, c1);
    *(us8*)&Bs[bi1] = f8bf(c2, c3);
    __syncthreads();

    bf16x8 a[4], b[4];
#pragma unroll
    for (int mi = 0; mi < 4; mi++)
      a[mi] = *(const bf16x8*)&As[(wm + mi * 16 + lr) * 32 + qk];
#pragma unroll
    for (int ni = 0; ni < 4; ni++)
      b[ni] = *(const bf16x8*)&Bs[(wn + ni * 16 + lr) * 32 + qk];
#pragma unroll
    for (int mi = 0; mi < 4; mi++)
#pragma unroll
      for (int ni = 0; ni < 4; ni++)
        acc[mi][ni] = __builtin_amdgcn_mfma_f32_16x16x32_bf16(a[mi], b[ni], acc[mi][ni], 0, 0, 0);
    __syncthreads();
  }

#pragma unroll
  for (int mi = 0; mi < 4; mi++)
#pragma unroll
    for (int ni = 0; ni < 4; ni++)
#pragma unroll
      for (int r = 0; r < 4; r++) {
        int row = wm + mi * 16 + (lane >> 4) * 4 + r;
        int col = wn + ni * 16 + lr;
        int i = m0 + row;
        if (i < ce)
          Gd[(size_t)(be + i) * H_DIM + n0 + col] = f2bf(acc[mi][ni][r]);
      }
}

// ---------------- K5: combine out[t] = Gd[slot1] + Gd[slot2] ----
__global__ void combine_kernel(const unsigned short* __restrict__ Gd,
                               const int* __restrict__ base,
                               const int* __restrict__ tok2slot,
                               float* __restrict__ out) {
  const int t = blockIdx.x;
  const int v1 = tok2slot[2 * t], v2 = tok2slot[2 * t + 1];
  const int s1 = base[v1 >> 12] + (v1 & 4095);
  const int s2 = base[v2 >> 12] + (v2 & 4095);
  const us4* r1 = (const us4*)(Gd + (size_t)s1 * H_DIM);
  const us4* r2 = (const us4*)(Gd + (size_t)s2 * H_DIM);
  float4* o = (float4*)(out + (size_t)t * H_DIM);
#pragma unroll
  for (int j = 0; j < 2; j++) {
    int i = j * 256 + threadIdx.x;
    us4 a = r1[i], b = r2[i];
    float4 r;
    r.x = bf2f(a.x) + bf2f(b.x);
    r.y = bf2f(a.y) + bf2f(b.y);
    r.z = bf2f(a.z) + bf2f(b.z);
    r.w = bf2f(a.w) + bf2f(b.w);
    o[i] = r;
  }
}

// ---------------- Launch ----------------
extern "C" void kernel_launch(void* const* d_in, const int* in_sizes, int n_in,
                              void* d_out, int out_size, void* d_ws, size_t ws_size,
                              hipStream_t stream) {
  (void)in_sizes; (void)n_in; (void)out_size; (void)ws_size;
  const float* x    = (const float*)d_in[0];
  const float* Wg   = (const float*)d_in[1];
  const float* W1   = (const float*)d_in[2];
  const float* W2   = (const float*)d_in[3];
  const float* W3   = (const float*)d_in[4];
  const float* bias = (const float*)d_in[5];
  float* out = (float*)d_out;

  char* ws = (char*)d_ws;
  const size_t OFF_CNT   = 0;
  const size_t OFF_BASE  = 64;
  const size_t OFF_T2S   = 1024;                       // 32 KB
  const size_t OFF_ROWS  = 65536;                      // 128 KB
  const size_t OFF_WTS   = OFF_ROWS + 131072;          // 128 KB
  const size_t OFF_EPAIR = OFF_WTS + 131072;           // 16 KB
  const size_t OFF_WPAIR = OFF_EPAIR + 16384;          // 32 KB
  const size_t OFF_XB    = 1048576;                    // 16 MB
  const size_t OFF_G     = OFF_XB + 16777216;          // 16 MB
  const size_t OFF_GD    = OFF_G + 16777216;           // 32 MB
  // total ~65 MB

  int*   cnt   = (int*)(ws + OFF_CNT);
  int*   base  = (int*)(ws + OFF_BASE);
  int*   t2s   = (int*)(ws + OFF_T2S);
  int*   rows  = (int*)(ws + OFF_ROWS);
  float* wts   = (float*)(ws + OFF_WTS);
  unsigned* epair = (unsigned*)(ws + OFF_EPAIR);
  float* wpair = (float*)(ws + OFF_WPAIR);
  unsigned short* Xb  = (unsigned short*)(ws + OFF_XB);
  unsigned short* G   = (unsigned short*)(ws + OFF_G);
  unsigned short* Gd  = (unsigned short*)(ws + OFF_GD);

  router_kernel<<<RB_ROUTER, 256, 0, stream>>>(x, Wg, bias, epair, wpair, Xb);

  compact_kernel<<<1, 512, 0, stream>>>(epair, wpair, cnt, base, rows, wts, t2s);

  dim3 g2(FFN_D / 64, T_TOK / 128, NE);
  upproj_fast<<<g2, 256, 0, stream>>>(Xb, W1, W3, cnt, base, rows, wts, G);

  dim3 g3(H_DIM / 128, T_TOK / 128, NE);
  downproj_fast<<<g3, 256, 0, stream>>>(G, W2, cnt, base, Gd);

  combine_kernel<<<T_TOK, 256, 0, stream>>>(Gd, base, t2s, out);
}

// Round 2
// 467.507 us; speedup vs baseline: 1.1972x; 1.1972x over previous
//
#include <hip/hip_runtime.h>
#include <hip/hip_bf16.h>

// MoE top-2/8, T=4096, H=2048, FFN=1024.
// Fused-conversion pipeline (no bf16 weight copies in HBM):
//   router  (router logits + x fp32->bf16 -> Xb)
//   compact (1 block, ballot prefix)
//   upproj  (A=Xb bf16 via global_load_lds; B=W1/W3 fp32 -> cvt_pk -> LDS,
//            B(k+1) loads issued inside MFMA region so barrier#2 drain covers them)
//   downproj(same pattern, B=W2 fp32)
//   combine

#define T_TOK 4096
#define H_DIM 2048
#define FFN_D 1024
#define NE    8

typedef __attribute__((ext_vector_type(8))) short          bf16x8;
typedef __attribute__((ext_vector_type(4))) float          f32x4;
typedef __attribute__((ext_vector_type(4))) unsigned short us4;
typedef __attribute__((ext_vector_type(8))) unsigned short us8;

#define RB_ROUTER 1024u

__device__ __forceinline__ unsigned short f2bf(float f) {
  unsigned u = __builtin_bit_cast(unsigned, f);
  u += 0x7fffu + ((u >> 16) & 1u);
  return (unsigned short)(u >> 16);
}
__device__ __forceinline__ float bf2f(unsigned short u) {
  return __builtin_bit_cast(float, ((unsigned)u) << 16);
}
// 8x fp32 -> 8x bf16 via v_cvt_pk_bf16_f32 (RNE; 4 insts instead of ~64)
__device__ __forceinline__ us8 f8bf(float4 a, float4 b) {
  union { us8 o; unsigned u[4]; } r;
  asm("v_cvt_pk_bf16_f32 %0, %1, %2" : "=v"(r.u[0]) : "v"(a.x), "v"(a.y));
  asm("v_cvt_pk_bf16_f32 %0, %1, %2" : "=v"(r.u[1]) : "v"(a.z), "v"(a.w));
  asm("v_cvt_pk_bf16_f32 %0, %1, %2" : "=v"(r.u[2]) : "v"(b.x), "v"(b.y));
  asm("v_cvt_pk_bf16_f32 %0, %1, %2" : "=v"(r.u[3]) : "v"(b.z), "v"(b.w));
  return r.o;
}
__device__ __forceinline__ void async16(const void* g, void* l) {
  __builtin_amdgcn_global_load_lds((const __attribute__((address_space(1))) void*)g,
                                   (__attribute__((address_space(3))) void*)l, 16, 0, 0);
}

// ---------------- K1: router (one wave per token) + x convert -> Xb ----
__global__ void router_kernel(const float* __restrict__ x,
                              const float* __restrict__ Wg,
                              const float* __restrict__ bias,
                              unsigned* __restrict__ epair,
                              float* __restrict__ wpair,
                              unsigned short* __restrict__ Xb) {
  const int wv   = threadIdx.x >> 6;
  const int lane = threadIdx.x & 63;
  const int t    = blockIdx.x * 4 + wv;

  const float4* xr = (const float4*)(x + (size_t)t * H_DIM);
  us4*          xb = (us4*)(Xb + (size_t)t * H_DIM);

  float acc[NE];
#pragma unroll
  for (int e = 0; e < NE; e++) acc[e] = 0.f;

#pragma unroll
  for (int j = 0; j < 8; j++) {
    int i4 = j * 64 + lane;
    float4 v = xr[i4];
    us4 d; d.x = f2bf(v.x); d.y = f2bf(v.y); d.z = f2bf(v.z); d.w = f2bf(v.w);
    xb[i4] = d;
#pragma unroll
    for (int e = 0; e < NE; e++) {
      float4 w = ((const float4*)(Wg + e * H_DIM))[i4];
      acc[e] += v.x * w.x + v.y * w.y + v.z * w.z + v.w * w.w;
    }
  }
#pragma unroll
  for (int e = 0; e < NE; e++) {
#pragma unroll
    for (int m = 32; m >= 1; m >>= 1) acc[e] += __shfl_xor(acc[e], m, 64);
  }

  if (lane == 0) {
    float sig[NE], sc[NE];
#pragma unroll
    for (int e = 0; e < NE; e++) {
      sig[e] = 1.f / (1.f + expf(-acc[e]));
      sc[e]  = sig[e] + bias[e];
    }
    int i1 = 0; float v1 = sc[0];
#pragma unroll
    for (int e = 1; e < NE; e++) if (sc[e] > v1) { v1 = sc[e]; i1 = e; }
    int i2 = -1; float v2 = -1e30f;
#pragma unroll
    for (int e = 0; e < NE; e++) if (e != i1 && sc[e] > v2) { v2 = sc[e]; i2 = e; }
    float w1 = sig[i1], w2 = sig[i2];
    float s = w1 + w2;
    epair[t] = (unsigned)i1 | ((unsigned)i2 << 8);
    wpair[2 * t]     = w1 / s;
    wpair[2 * t + 1] = w2 / s;
  }
}

// ---------------- K2: compaction, ONE block, 8 waves (wave e scans all tokens) ----
__global__ void compact_kernel(const unsigned* __restrict__ epair,
                               const float* __restrict__ wpair,
                               int* __restrict__ cnt,
                               int* __restrict__ base,
                               int* __restrict__ rows,
                               float* __restrict__ wts,
                               int* __restrict__ t2s) {
  const int e    = threadIdx.x >> 6;
  const int lane = threadIdx.x & 63;
  const unsigned long long ltmask = ((unsigned long long)1 << lane) - 1;
  __shared__ int cnts[NE];

  int count = 0;
  for (int c = 0; c < T_TOK; c += 64) {
    int t = c + lane;
    unsigned ep = epair[t];
    bool m1 = ((ep & 255u) == (unsigned)e);
    bool m2 = (((ep >> 8) & 255u) == (unsigned)e);
    unsigned long long b1 = __ballot(m1);
    if (m1) {
      int p = count + __popcll(b1 & ltmask);
      rows[e * T_TOK + p] = t;
      wts [e * T_TOK + p] = wpair[2 * t];
      t2s[2 * t] = (e << 12) | p;
    }
    count += __popcll(b1);
    unsigned long long b2 = __ballot(m2);
    if (m2) {
      int p = count + __popcll(b2 & ltmask);
      rows[e * T_TOK + p] = t;
      wts [e * T_TOK + p] = wpair[2 * t + 1];
      t2s[2 * t + 1] = (e << 12) | p;
    }
    count += __popcll(b2);
  }
  if (lane == 0) { cnts[e] = count; cnt[e] = count; }
  __syncthreads();
  if (threadIdx.x == 0) {
    int s = 0;
    for (int i = 0; i < NE; i++) { base[i] = s; s += cnts[i]; }
    base[NE] = s;
  }
}

// ---------------- K3: up-proj BM=128 x BN=64 (x2 mats), BK=32.
// B staged from fp32 with cvt_pk; next-K B loads issued inside MFMA region. ----
__launch_bounds__(256)
__global__ void upproj_fast(const unsigned short* __restrict__ Xb,
                            const float* __restrict__ W1,
                            const float* __restrict__ W3,
                            const int* __restrict__ cnt,
                            const int* __restrict__ base,
                            const int* __restrict__ rows,
                            const float* __restrict__ wts,
                            unsigned short* __restrict__ G) {
  const int e  = blockIdx.z;
  const int m0 = blockIdx.y * 128;
  const int n0 = blockIdx.x * 64;
  const int ce = cnt[e];
  if (m0 >= ce) return;

  __shared__ __align__(16) unsigned short As [128 * 32];
  __shared__ __align__(16) unsigned short B1s[64 * 32];
  __shared__ __align__(16) unsigned short B3s[64 * 32];
  __shared__ int   t_ids[128];
  __shared__ float w_lds[128];

  const int tid = threadIdx.x;
  if (tid < 128) {
    int i = m0 + tid;
    if (i < ce) { t_ids[tid] = rows[e * T_TOK + i]; w_lds[tid] = wts[e * T_TOK + i]; }
    else        { t_ids[tid] = 0;                   w_lds[tid] = 0.f; }
  }
  __syncthreads();

  const int lane = tid & 63;
  const int wv   = tid >> 6;

  const unsigned short* gA[2];
#pragma unroll
  for (int c = 0; c < 2; c++) {
    int r = wv * 32 + c * 16 + (lane >> 2);
    gA[c] = Xb + (size_t)t_ids[r] * H_DIM + (lane & 3) * 8;
  }
  unsigned short* lA0 = &As[(wv * 32 + 0)  * 32];
  unsigned short* lA1 = &As[(wv * 32 + 16) * 32];

  const int brow = n0 + wv * 16 + (lane >> 2);
  const float* gB1 = W1 + (size_t)e * FFN_D * H_DIM + (size_t)brow * H_DIM + (lane & 3) * 8;
  const float* gB3 = W3 + (size_t)e * FFN_D * H_DIM + (size_t)brow * H_DIM + (lane & 3) * 8;
  const int bidx = (wv * 16 + (lane >> 2)) * 32 + (lane & 3) * 8;

  const int wm = (wv & 1) * 64;
  const int wn = (wv >> 1) * 32;
  const int qk = (lane >> 4) * 8;
  const int lr = lane & 15;

  f32x4 acc1[4][2], acc3[4][2];
#pragma unroll
  for (int mi = 0; mi < 4; mi++)
#pragma unroll
    for (int ni = 0; ni < 2; ni++) { acc1[mi][ni] = (f32x4)0.f; acc3[mi][ni] = (f32x4)0.f; }

  // prologue: B(0) into regs
  float4 p0 = *(const float4*)(gB1 + 0);
  float4 p1 = *(const float4*)(gB1 + 4);
  float4 p2 = *(const float4*)(gB3 + 0);
  float4 p3 = *(const float4*)(gB3 + 4);

  for (int kt = 0; kt < H_DIM; kt += 32) {
    async16(gA[0] + kt, lA0);
    async16(gA[1] + kt, lA1);
    // convert current B (regs resident since barrier#2 of previous iter)
    *(us8*)&B1s[bidx] = f8bf(p0, p1);
    *(us8*)&B3s[bidx] = f8bf(p2, p3);
    __syncthreads();   // drains A async16 + B ds_writes

    // issue next-iter B loads NOW: latency hidden under ds_read+MFMA,
    // completion guaranteed by barrier#2's vmcnt(0) drain.
    if (kt + 32 < H_DIM) {
      p0 = *(const float4*)(gB1 + kt + 32);
      p1 = *(const float4*)(gB1 + kt + 36);
      p2 = *(const float4*)(gB3 + kt + 32);
      p3 = *(const float4*)(gB3 + kt + 36);
    }

    bf16x8 a[4], b1[2], b3[2];
#pragma unroll
    for (int mi = 0; mi < 4; mi++)
      a[mi] = *(const bf16x8*)&As[(wm + mi * 16 + lr) * 32 + qk];
#pragma unroll
    for (int ni = 0; ni < 2; ni++) {
      b1[ni] = *(const bf16x8*)&B1s[(wn + ni * 16 + lr) * 32 + qk];
      b3[ni] = *(const bf16x8*)&B3s[(wn + ni * 16 + lr) * 32 + qk];
    }
#pragma unroll
    for (int mi = 0; mi < 4; mi++)
#pragma unroll
      for (int ni = 0; ni < 2; ni++) {
        acc1[mi][ni] = __builtin_amdgcn_mfma_f32_16x16x32_bf16(a[mi], b1[ni], acc1[mi][ni], 0, 0, 0);
        acc3[mi][ni] = __builtin_amdgcn_mfma_f32_16x16x32_bf16(a[mi], b3[ni], acc3[mi][ni], 0, 0, 0);
      }
    __syncthreads();   // drains next-iter B loads (covered by MFMA region)
  }

  const int be = base[e];
#pragma unroll
  for (int mi = 0; mi < 4; mi++)
#pragma unroll
    for (int ni = 0; ni < 2; ni++)
#pragma unroll
      for (int r = 0; r < 4; r++) {
        int row = wm + mi * 16 + (lane >> 4) * 4 + r;
        int col = wn + ni * 16 + lr;
        int i = m0 + row;
        if (i < ce) {
          float h1 = acc1[mi][ni][r];
          float h3 = acc3[mi][ni][r];
          float g  = h1 / (1.f + expf(-h1)) * h3 * w_lds[row];
          G[(size_t)(be + i) * FFN_D + n0 + col] = f2bf(g);
        }
      }
}

// ---------------- K4: down-proj BM=128 x BN=128, BK=32 -> bf16 Gd. ----
__launch_bounds__(256)
__global__ void downproj_fast(const unsigned short* __restrict__ G,
                              const float* __restrict__ W2,
                              const int* __restrict__ cnt,
                              const int* __restrict__ base,
                              unsigned short* __restrict__ Gd) {
  const int e  = blockIdx.z;
  const int m0 = blockIdx.y * 128;
  const int n0 = blockIdx.x * 128;
  const int ce = cnt[e];
  if (m0 >= ce) return;
  const int be = base[e];

  __shared__ __align__(16) unsigned short As[128 * 32];
  __shared__ __align__(16) unsigned short Bs[128 * 32];

  const int tid  = threadIdx.x;
  const int lane = tid & 63;
  const int wv   = tid >> 6;

  const unsigned short* gA[2];
#pragma unroll
  for (int c = 0; c < 2; c++) {
    int r = m0 + wv * 32 + c * 16 + (lane >> 2);
    if (r >= ce) r = ce - 1;
    gA[c] = G + (size_t)(be + r) * FFN_D + (lane & 3) * 8;
  }
  unsigned short* lA[2] = { &As[(wv * 32 + 0) * 32], &As[(wv * 32 + 16) * 32] };

  const int rb0 = wv * 32 + (lane >> 2);
  const int rb1 = rb0 + 16;
  const float* gB0 = W2 + (size_t)e * H_DIM * FFN_D + (size_t)(n0 + rb0) * FFN_D + (lane & 3) * 8;
  const float* gB1 = W2 + (size_t)e * H_DIM * FFN_D + (size_t)(n0 + rb1) * FFN_D + (lane & 3) * 8;
  const int bi0 = rb0 * 32 + (lane & 3) * 8;
  const int bi1 = rb1 * 32 + (lane & 3) * 8;

  const int wm = (wv & 1) * 64;
  const int wn = (wv >> 1) * 64;
  const int qk = (lane >> 4) * 8;
  const int lr = lane & 15;

  f32x4 acc[4][4];
#pragma unroll
  for (int mi = 0; mi < 4; mi++)
#pragma unroll
    for (int ni = 0; ni < 4; ni++) acc[mi][ni] = (f32x4)0.f;

  float4 p0 = *(const float4*)(gB0 + 0);
  float4 p1 = *(const float4*)(gB0 + 4);
  float4 p2 = *(const float4*)(gB1 + 0);
  float4 p3 = *(const float4*)(gB1 + 4);

  for (int kt = 0; kt < FFN_D; kt += 32) {
    async16(gA[0] + kt, lA[0]);
    async16(gA[1] + kt, lA[1]);
    *(us8*)&Bs[bi0] = f8bf(p0, p1);
    *(us8*)&Bs[bi1] = f8bf(p2, p3);
    __syncthreads();

    if (kt + 32 < FFN_D) {
      p0 = *(const float4*)(gB0 + kt + 32);
      p1 = *(const float4*)(gB0 + kt + 36);
      p2 = *(const float4*)(gB1 + kt + 32);
      p3 = *(const float4*)(gB1 + kt + 36);
    }

    bf16x8 a[4], b[4];
#pragma unroll
    for (int mi = 0; mi < 4; mi++)
      a[mi] = *(const bf16x8*)&As[(wm + mi * 16 + lr) * 32 + qk];
#pragma unroll
    for (int ni = 0; ni < 4; ni++)
      b[ni] = *(const bf16x8*)&Bs[(wn + ni * 16 + lr) * 32 + qk];
#pragma unroll
    for (int mi = 0; mi < 4; mi++)
#pragma unroll
      for (int ni = 0; ni < 4; ni++)
        acc[mi][ni] = __builtin_amdgcn_mfma_f32_16x16x32_bf16(a[mi], b[ni], acc[mi][ni], 0, 0, 0);
    __syncthreads();
  }

#pragma unroll
  for (int mi = 0; mi < 4; mi++)
#pragma unroll
    for (int ni = 0; ni < 4; ni++)
#pragma unroll
      for (int r = 0; r < 4; r++) {
        int row = wm + mi * 16 + (lane >> 4) * 4 + r;
        int col = wn + ni * 16 + lr;
        int i = m0 + row;
        if (i < ce)
          Gd[(size_t)(be + i) * H_DIM + n0 + col] = f2bf(acc[mi][ni][r]);
      }
}

// ---------------- K5: combine out[t] = Gd[slot1] + Gd[slot2] ----
__global__ void combine_kernel(const unsigned short* __restrict__ Gd,
                               const int* __restrict__ base,
                               const int* __restrict__ tok2slot,
                               float* __restrict__ out) {
  const int t = blockIdx.x;
  const int v1 = tok2slot[2 * t], v2 = tok2slot[2 * t + 1];
  const int s1 = base[v1 >> 12] + (v1 & 4095);
  const int s2 = base[v2 >> 12] + (v2 & 4095);
  const us4* r1 = (const us4*)(Gd + (size_t)s1 * H_DIM);
  const us4* r2 = (const us4*)(Gd + (size_t)s2 * H_DIM);
  float4* o = (float4*)(out + (size_t)t * H_DIM);
#pragma unroll
  for (int j = 0; j < 2; j++) {
    int i = j * 256 + threadIdx.x;
    us4 a = r1[i], b = r2[i];
    float4 r;
    r.x = bf2f(a.x) + bf2f(b.x);
    r.y = bf2f(a.y) + bf2f(b.y);
    r.z = bf2f(a.z) + bf2f(b.z);
    r.w = bf2f(a.w) + bf2f(b.w);
    o[i] = r;
  }
}

// ---------------- Launch ----------------
extern "C" void kernel_launch(void* const* d_in, const int* in_sizes, int n_in,
                              void* d_out, int out_size, void* d_ws, size_t ws_size,
                              hipStream_t stream) {
  (void)in_sizes; (void)n_in; (void)out_size; (void)ws_size;
  const float* x    = (const float*)d_in[0];
  const float* Wg   = (const float*)d_in[1];
  const float* W1   = (const float*)d_in[2];
  const float* W2   = (const float*)d_in[3];
  const float* W3   = (const float*)d_in[4];
  const float* bias = (const float*)d_in[5];
  float* out = (float*)d_out;

  char* ws = (char*)d_ws;
  const size_t OFF_CNT   = 0;
  const size_t OFF_BASE  = 64;
  const size_t OFF_T2S   = 1024;                       // 32 KB
  const size_t OFF_ROWS  = 65536;                      // 128 KB
  const size_t OFF_WTS   = OFF_ROWS + 131072;          // 128 KB
  const size_t OFF_EPAIR = OFF_WTS + 131072;           // 16 KB
  const size_t OFF_WPAIR = OFF_EPAIR + 16384;          // 32 KB
  const size_t OFF_XB    = 1048576;                    // 16 MB
  const size_t OFF_G     = OFF_XB + 16777216;          // 16 MB
  const size_t OFF_GD    = OFF_G + 16777216;           // 32 MB
  // total ~65 MB

  int*   cnt   = (int*)(ws + OFF_CNT);
  int*   base  = (int*)(ws + OFF_BASE);
  int*   t2s   = (int*)(ws + OFF_T2S);
  int*   rows  = (int*)(ws + OFF_ROWS);
  float* wts   = (float*)(ws + OFF_WTS);
  unsigned* epair = (unsigned*)(ws + OFF_EPAIR);
  float* wpair = (float*)(ws + OFF_WPAIR);
  unsigned short* Xb  = (unsigned short*)(ws + OFF_XB);
  unsigned short* G   = (unsigned short*)(ws + OFF_G);
  unsigned short* Gd  = (unsigned short*)(ws + OFF_GD);

  router_kernel<<<RB_ROUTER, 256, 0, stream>>>(x, Wg, bias, epair, wpair, Xb);

  compact_kernel<<<1, 512, 0, stream>>>(epair, wpair, cnt, base, rows, wts, t2s);

  dim3 g2(FFN_D / 64, T_TOK / 128, NE);
  upproj_fast<<<g2, 256, 0, stream>>>(Xb, W1, W3, cnt, base, rows, wts, G);

  dim3 g3(H_DIM / 128, T_TOK / 128, NE);
  downproj_fast<<<g3, 256, 0, stream>>>(G, W2, cnt, base, Gd);

  combine_kernel<<<T_TOK, 256, 0, stream>>>(Gd, base, t2s, out);
}